// Round 3
// baseline (229.781 us; speedup 1.0000x reference)
//
#include <hip/hip_runtime.h>
#include <math.h>

// Problem constants (fixed by reference)
#define BB 4
#define NN 512
#define DD 128
#define HH 8
#define KK 16

// ---------------------------------------------------------------------------
// Kernel 1: Q/K/V projections (unchanged, verified round 1).
// Store as [b][n][p] with p = h*16 + k; Q pre-scaled by 1/sqrt(16) = 0.25.
// ---------------------------------------------------------------------------
__global__ __launch_bounds__(128) void proj_kernel(
    const float* __restrict__ q,
    const float* __restrict__ Wq,
    const float* __restrict__ Wk,
    const float* __restrict__ Wv,
    float* __restrict__ Qs,
    float* __restrict__ Kp,
    float* __restrict__ Vp)
{
    __shared__ float qrow[DD];
    const int bn = blockIdx.x;
    const int t = threadIdx.x;          // 0..127 -> p = h*16+k
    qrow[t] = q[(size_t)bn * DD + t];
    __syncthreads();
    const int h = t >> 4;
    const int k = t & 15;
    const float* wq = Wq + (size_t)h * DD * KK + k;   // stride KK over d
    const float* wk = Wk + (size_t)h * DD * KK + k;
    const float* wv = Wv + (size_t)h * DD * KK + k;
    float aq = 0.f, ak = 0.f, av = 0.f;
#pragma unroll 16
    for (int d = 0; d < DD; ++d) {
        const float x = qrow[d];
        aq = fmaf(x, wq[(size_t)d * KK], aq);
        ak = fmaf(x, wk[(size_t)d * KK], ak);
        av = fmaf(x, wv[(size_t)d * KK], av);
    }
    Qs[(size_t)bn * DD + t] = aq * 0.25f;   // norm = 1/sqrt(KEY_DIM=16)
    Kp[(size_t)bn * DD + t] = ak;
    Vp[(size_t)bn * DD + t] = av;
}

// ---------------------------------------------------------------------------
// Kernel 2: fused edge-bias + attention + out-projection.
// R3: 32-lane-per-row layout (ev[8][4] = 32 VGPR) + register double-buffered
// prefetch in the m-phase so 4 global loads stay in flight through compute
// (counted vmcnt, never drained). __launch_bounds__(256,4) -> 4 waves/SIMD.
// Per pass: 2 rows, lane c = lane&31 owns 4-float chunk d0 = c*4;
// fold over c: steps ^16,^8,^4 (value-halving) then ^2,^1 (accumulate);
// lane c&3==0 holds head (c>>2)&7. ds_write banks (4h+m)&31: conflict-free.
// ---------------------------------------------------------------------------
__global__ __launch_bounds__(256, 4) void attn_kernel(
    const float* __restrict__ e,
    const float* __restrict__ Ev,      // [H][D]
    const float* __restrict__ Qs,      // [B][N][128], pre-scaled
    const float* __restrict__ Kp,      // [B][N][128]
    const float* __restrict__ Vp,      // [B][N][128]
    const float* __restrict__ Wout,    // [H*16][128] -> [p][e]
    float* __restrict__ out)           // [B][N][128]
{
    __shared__ float comp[HH][NN + 4];   // stride 516 words
    __shared__ float headsv[HH * KK];

    const int bn   = blockIdx.x;
    const int b    = bn >> 9;            // / NN
    const int tid  = threadIdx.x;
    const int wave = tid >> 6;
    const int lane = tid & 63;
    const int r    = lane >> 5;          // 0..1 : row within a pass
    const int c    = lane & 31;          // 4-float chunk index
    const int d0   = c * 4;
    const int myh  = c >> 2;             // head owning this lane's QK chunk
    const int hidx = (c >> 2) & 7;       // head this lane holds after fold

    // E_val1 fragment: ev[h][j] = Ev[h][d0+j]  (32 VGPRs)
    float ev[HH][4];
#pragma unroll
    for (int h = 0; h < HH; ++h) {
        const float4 a = *(const float4*)(Ev + h * DD + d0);
        ev[h][0] = a.x; ev[h][1] = a.y; ev[h][2] = a.z; ev[h][3] = a.w;
    }
    // Q fragment for this (b,n): positions p = d0..d0+3 (within head myh)
    const float4 qf = *(const float4*)(Qs + (size_t)bn * DD + d0);

    const int mb = wave * 128 + r;                        // row of pass 0
    const float* epl = e  + (size_t)bn * NN * DD + (size_t)mb * DD + d0;
    const float* kpl = Kp + (size_t)b  * NN * DD + (size_t)mb * DD + d0;
    // pass p -> row mb + 2p -> float offset p*256

    const bool f16 = (c & 16) != 0;
    const bool f8  = (c & 8)  != 0;
    const bool f4  = (c & 4)  != 0;

    auto do_pass = [&](const float4 ee, const float4 kk, const int m) {
        float kq;
        kq = kk.x * qf.x;
        kq = fmaf(kk.y, qf.y, kq);
        kq = fmaf(kk.z, qf.z, kq);
        kq = fmaf(kk.w, qf.w, kq);
        float acc[HH];
#pragma unroll
        for (int h = 0; h < HH; ++h) {
            float s = (myh == h) ? kq : 0.f;
            s = fmaf(ee.x, ev[h][0], s);
            s = fmaf(ee.y, ev[h][1], s);
            s = fmaf(ee.z, ev[h][2], s);
            s = fmaf(ee.w, ev[h][3], s);
            acc[h] = s;
        }
        // fold ^16 : 8 -> 4 values
        float t4[4];
#pragma unroll
        for (int j = 0; j < 4; ++j) {
            const float keep = f16 ? acc[j + 4] : acc[j];
            const float send = f16 ? acc[j]     : acc[j + 4];
            t4[j] = keep + __shfl_xor(send, 16);
        }
        // fold ^8 : 4 -> 2
        float t2[2];
#pragma unroll
        for (int j = 0; j < 2; ++j) {
            const float keep = f8 ? t4[j + 2] : t4[j];
            const float send = f8 ? t4[j]     : t4[j + 2];
            t2[j] = keep + __shfl_xor(send, 8);
        }
        // fold ^4 : 2 -> 1
        float w;
        {
            const float keep = f4 ? t2[1] : t2[0];
            const float send = f4 ? t2[0] : t2[1];
            w = keep + __shfl_xor(send, 4);
        }
        // accumulate remaining lane bits 1,0 (same head within 4-lane group)
        w += __shfl_xor(w, 2);
        w += __shfl_xor(w, 1);
        if ((c & 3) == 0) comp[hidx][m] = w;
    };

#define LDF4(p, base) (*(const float4*)((base) + (size_t)(p) * 256))

    // prologue: group 0 (passes 0,1) into gang A
    float4 ea0 = LDF4(0, epl), ea1 = LDF4(1, epl);
    float4 ka0 = LDF4(0, kpl), ka1 = LDF4(1, kpl);
    float4 eb0, eb1, kb0, kb1;

    for (int g = 0; g < 32; g += 2) {
        // prefetch group g+1 (passes 2g+2, 2g+3) into gang B
        {
            const int p0 = 2 * g + 2, p1 = 2 * g + 3;
            eb0 = LDF4(p0, epl); eb1 = LDF4(p1, epl);
            kb0 = LDF4(p0, kpl); kb1 = LDF4(p1, kpl);
        }
        // compute group g (passes 2g, 2g+1): rows mb+4g, mb+4g+2
        do_pass(ea0, ka0, mb + 4 * g);
        do_pass(ea1, ka1, mb + 4 * g + 2);
        // prefetch group g+2 (passes 2g+4, 2g+5) into gang A
        if (g + 2 < 32) {
            const int p0 = 2 * g + 4, p1 = 2 * g + 5;
            ea0 = LDF4(p0, epl); ea1 = LDF4(p1, epl);
            ka0 = LDF4(p0, kpl); ka1 = LDF4(p1, kpl);
        }
        // compute group g+1 (passes 2g+2, 2g+3): rows mb+4g+4, mb+4g+6
        do_pass(eb0, kb0, mb + 4 * g + 4);
        do_pass(eb1, kb1, mb + 4 * g + 6);
    }
#undef LDF4
    __syncthreads();

    // ---- softmax + PV: wave handles heads 2w, 2w+1 (unchanged from R2) ----
    const float* vbase = Vp + (size_t)b * NN * DD;
#pragma unroll
    for (int hh = 0; hh < 2; ++hh) {
        const int h = wave * 2 + hh;
        float mx = -3.0e38f;
#pragma unroll
        for (int i = 0; i < 8; ++i) mx = fmaxf(mx, comp[h][lane + i * 64]);
#pragma unroll
        for (int mask = 1; mask <= 32; mask <<= 1)
            mx = fmaxf(mx, __shfl_xor(mx, mask));

        float psum = 0.f;
        float av[KK];
#pragma unroll
        for (int v = 0; v < KK; ++v) av[v] = 0.f;
#pragma unroll
        for (int i = 0; i < 8; ++i) {
            const int m = lane + i * 64;
            const float p = __expf(comp[h][m] - mx);
            psum += p;
            const float* vp = vbase + (size_t)m * DD + h * KK;
            const float4 v0 = *(const float4*)(vp);
            const float4 v1 = *(const float4*)(vp + 4);
            const float4 v2 = *(const float4*)(vp + 8);
            const float4 v3 = *(const float4*)(vp + 12);
            av[0]  = fmaf(p, v0.x, av[0]);  av[1]  = fmaf(p, v0.y, av[1]);
            av[2]  = fmaf(p, v0.z, av[2]);  av[3]  = fmaf(p, v0.w, av[3]);
            av[4]  = fmaf(p, v1.x, av[4]);  av[5]  = fmaf(p, v1.y, av[5]);
            av[6]  = fmaf(p, v1.z, av[6]);  av[7]  = fmaf(p, v1.w, av[7]);
            av[8]  = fmaf(p, v2.x, av[8]);  av[9]  = fmaf(p, v2.y, av[9]);
            av[10] = fmaf(p, v2.z, av[10]); av[11] = fmaf(p, v2.w, av[11]);
            av[12] = fmaf(p, v3.x, av[12]); av[13] = fmaf(p, v3.y, av[13]);
            av[14] = fmaf(p, v3.z, av[14]); av[15] = fmaf(p, v3.w, av[15]);
        }
        // psum: full butterfly (all lanes need it)
#pragma unroll
        for (int mask = 1; mask <= 32; mask <<= 1)
            psum += __shfl_xor(psum, mask);

        // av[16] fold over 64 lanes: v index bits come from lane bits 5..2
        const bool s5 = (lane & 32) != 0;
        float a8[8];
#pragma unroll
        for (int j = 0; j < 8; ++j) {
            const float keep = s5 ? av[j + 8] : av[j];
            const float send = s5 ? av[j]     : av[j + 8];
            a8[j] = keep + __shfl_xor(send, 32);
        }
        const bool s4 = (lane & 16) != 0;
        float a4[4];
#pragma unroll
        for (int j = 0; j < 4; ++j) {
            const float keep = s4 ? a8[j + 4] : a8[j];
            const float send = s4 ? a8[j]     : a8[j + 4];
            a4[j] = keep + __shfl_xor(send, 16);
        }
        const bool s3 = (lane & 8) != 0;
        float a2[2];
#pragma unroll
        for (int j = 0; j < 2; ++j) {
            const float keep = s3 ? a4[j + 2] : a4[j];
            const float send = s3 ? a4[j]     : a4[j + 2];
            a2[j] = keep + __shfl_xor(send, 8);
        }
        const bool s2 = (lane & 4) != 0;
        float a1;
        {
            const float keep = s2 ? a2[1] : a2[0];
            const float send = s2 ? a2[0] : a2[1];
            a1 = keep + __shfl_xor(send, 4);
        }
        a1 += __shfl_xor(a1, 2);
        a1 += __shfl_xor(a1, 1);
        if ((lane & 3) == 0)
            headsv[h * KK + (lane >> 2)] = a1 / psum;
    }
    __syncthreads();

    // ---- out projection: out[bn][t] = sum_p headsv[p] * Wout[p][t] ----
    if (tid < DD) {
        float o = 0.f;
#pragma unroll 8
        for (int p = 0; p < HH * KK; ++p)
            o = fmaf(headsv[p], Wout[(size_t)p * DD + tid], o);
        out[(size_t)bn * DD + tid] = o;
    }
}

extern "C" void kernel_launch(void* const* d_in, const int* in_sizes, int n_in,
                              void* d_out, int out_size, void* d_ws, size_t ws_size,
                              hipStream_t stream) {
    const float* q    = (const float*)d_in[0];
    const float* e    = (const float*)d_in[1];
    const float* Wq   = (const float*)d_in[2];
    const float* Wk   = (const float*)d_in[3];
    const float* Wv   = (const float*)d_in[4];
    const float* Ev   = (const float*)d_in[5];
    const float* Wout = (const float*)d_in[6];
    float* out = (float*)d_out;

    float* Qs = (float*)d_ws;                 // [B][N][128]
    float* Kp = Qs + (size_t)BB * NN * DD;    // [B][N][128]
    float* Vp = Kp + (size_t)BB * NN * DD;    // [B][N][128]

    proj_kernel<<<BB * NN, 128, 0, stream>>>(q, Wq, Wk, Wv, Qs, Kp, Vp);
    attn_kernel<<<BB * NN, 256, 0, stream>>>(e, Ev, Qs, Kp, Vp, Wout, out);
}

// Round 4
// 200.728 us; speedup vs baseline: 1.1447x; 1.1447x over previous
//
#include <hip/hip_runtime.h>
#include <math.h>

// Problem constants (fixed by reference)
#define BB 4
#define NN 512
#define DD 128
#define HH 8
#define KK 16

// ---------------------------------------------------------------------------
// Kernel 1: Q/K/V projections (verified since R1).
// Store as [b][n][p] with p = h*16 + k; Q pre-scaled by 1/sqrt(16) = 0.25.
// ---------------------------------------------------------------------------
__global__ __launch_bounds__(128) void proj_kernel(
    const float* __restrict__ q,
    const float* __restrict__ Wq,
    const float* __restrict__ Wk,
    const float* __restrict__ Wv,
    float* __restrict__ Qs,
    float* __restrict__ Kp,
    float* __restrict__ Vp)
{
    __shared__ float qrow[DD];
    const int bn = blockIdx.x;
    const int t = threadIdx.x;          // 0..127 -> p = h*16+k
    qrow[t] = q[(size_t)bn * DD + t];
    __syncthreads();
    const int h = t >> 4;
    const int k = t & 15;
    const float* wq = Wq + (size_t)h * DD * KK + k;   // stride KK over d
    const float* wk = Wk + (size_t)h * DD * KK + k;
    const float* wv = Wv + (size_t)h * DD * KK + k;
    float aq = 0.f, ak = 0.f, av = 0.f;
#pragma unroll 16
    for (int d = 0; d < DD; ++d) {
        const float x = qrow[d];
        aq = fmaf(x, wq[(size_t)d * KK], aq);
        ak = fmaf(x, wk[(size_t)d * KK], ak);
        av = fmaf(x, wv[(size_t)d * KK], av);
    }
    Qs[(size_t)bn * DD + t] = aq * 0.25f;   // norm = 1/sqrt(KEY_DIM=16)
    Kp[(size_t)bn * DD + t] = ak;
    Vp[(size_t)bn * DD + t] = av;
}

// ---------------------------------------------------------------------------
// Kernel 2: V transpose Vp[b][m][p] -> Vt[b][p][m]  (p = h*16+v).
// LDS-staged so BOTH global sides are coalesced. 32 blocks, ~2 us.
// ---------------------------------------------------------------------------
__global__ __launch_bounds__(256) void vt_kernel(
    const float* __restrict__ Vp, float* __restrict__ Vt)
{
    __shared__ float tile[64][129];       // +1 pad: transposed read conflict-free
    const int b  = blockIdx.x >> 3;       // 8 m-tiles of 64 per b
    const int m0 = (blockIdx.x & 7) * 64;
    const int t  = threadIdx.x;
    const float* src = Vp + ((size_t)b * NN + m0) * DD;
#pragma unroll
    for (int j = 0; j < 8; ++j) {
        const int idx4 = t + j * 256;     // float4 index in [0,2048)
        const float4 v = *(const float4*)(src + (size_t)idx4 * 4);
        const int r = idx4 >> 5, c = (idx4 & 31) * 4;
        tile[r][c] = v.x; tile[r][c+1] = v.y; tile[r][c+2] = v.z; tile[r][c+3] = v.w;
    }
    __syncthreads();
    const int m = t & 63;                 // wave-uniform p per 64-group
#pragma unroll
    for (int p0 = 0; p0 < 128; p0 += 4) {
        const int p = p0 + (t >> 6);
        Vt[((size_t)b * DD + p) * NN + m0 + m] = tile[m][p];
    }
}

// ---------------------------------------------------------------------------
// Kernel 3: QK^T -> QKT[b][n][h][m]  (Q pre-scaled, so norm included).
// 512 blocks, each does 4 n-rows sharing one K-stream (L2). Lane dc owns
// half-head dc>>1; 1 shfl completes the 16-dot.
// ---------------------------------------------------------------------------
__global__ __launch_bounds__(256) void qkt_kernel(
    const float* __restrict__ Qs, const float* __restrict__ Kp,
    float* __restrict__ QKT)
{
    const int b    = blockIdx.x >> 7;     // 128 n4-tiles per b
    const int n4   = blockIdx.x & 127;
    const int tid  = threadIdx.x;
    const int wave = tid >> 6;
    const int lane = tid & 63;
    const int sub  = lane >> 4;
    const int dc   = lane & 15;
    const int d0   = dc * 8;

    float qf[4][8];
#pragma unroll
    for (int j = 0; j < 4; ++j) {
        const float* qp = Qs + ((size_t)b * NN + n4 * 4 + j) * DD + d0;
        const float4 a = *(const float4*)qp;
        const float4 c = *(const float4*)(qp + 4);
        qf[j][0]=a.x; qf[j][1]=a.y; qf[j][2]=a.z; qf[j][3]=a.w;
        qf[j][4]=c.x; qf[j][5]=c.y; qf[j][6]=c.z; qf[j][7]=c.w;
    }
    const float* kbase = Kp + (size_t)b * NN * DD;
    for (int i = 0; i < 32; ++i) {
        const int m = wave * 128 + i * 4 + sub;
        const float* kp = kbase + (size_t)m * DD + d0;
        const float4 k0 = *(const float4*)kp;
        const float4 k1 = *(const float4*)(kp + 4);
        float kr[8];
        kr[0]=k0.x; kr[1]=k0.y; kr[2]=k0.z; kr[3]=k0.w;
        kr[4]=k1.x; kr[5]=k1.y; kr[6]=k1.z; kr[7]=k1.w;
#pragma unroll
        for (int j = 0; j < 4; ++j) {
            float s = kr[0] * qf[j][0];
#pragma unroll
            for (int u = 1; u < 8; ++u) s = fmaf(kr[u], qf[j][u], s);
            s += __shfl_xor(s, 1);        // combine the two half-head lanes
            if ((dc & 1) == 0)
                QKT[(((size_t)b * NN + n4 * 4 + j) * HH + (dc >> 1)) * NN + m] = s;
        }
    }
}

// ---------------------------------------------------------------------------
// Kernel 4: fused edge-bias + softmax + PV + out-projection.
// R4: the m-loop is a PURE e-stream (vmcnt queue = HBM only; K removed).
// 3-buffer / 2-ahead register prefetch, static buffer names. R2's 16-lane-row
// fold (9 DS per 2 KB). Softmax adds QKT (coalesced global) to the LDS
// edge-bias; PV reads transposed Vt coalesced.
// ---------------------------------------------------------------------------
__global__ __launch_bounds__(256) void attn_kernel(
    const float* __restrict__ e,
    const float* __restrict__ Ev,      // [H][D]
    const float* __restrict__ QKT,     // [B][N][H][M]
    const float* __restrict__ Vt,      // [B][P][M], p = h*16+v
    const float* __restrict__ Wout,    // [P][E]
    float* __restrict__ out)           // [B][N][E]
{
    __shared__ float comp[HH][NN + 4];   // stride 516: write banks 4h+sub+m distinct
    __shared__ float headsv[HH * KK];

    const int bn   = blockIdx.x;
    const int b    = bn >> 9;
    const int tid  = threadIdx.x;
    const int wave = tid >> 6;
    const int lane = tid & 63;
    const int sub  = lane >> 4;          // row within a pass (4 rows/pass)
    const int dc   = lane & 15;          // 8-float chunk
    const int d0   = dc * 8;

    float ev[HH][8];
#pragma unroll
    for (int h = 0; h < HH; ++h) {
        const float4 a = *(const float4*)(Ev + h * DD + d0);
        const float4 c = *(const float4*)(Ev + h * DD + d0 + 4);
        ev[h][0]=a.x; ev[h][1]=a.y; ev[h][2]=a.z; ev[h][3]=a.w;
        ev[h][4]=c.x; ev[h][5]=c.y; ev[h][6]=c.z; ev[h][7]=c.w;
    }

    const bool hi8 = (dc & 8) != 0;
    const bool hi4 = (dc & 4) != 0;
    const bool hi2 = (dc & 2) != 0;
    const float* epl = e + (size_t)bn * NN * DD
                         + (size_t)(wave * 128 + sub) * DD + d0;
    // pass p covers rows wave*128 + p*4 + sub  -> float offset p*512

    auto do_pass = [&](const float4 e0, const float4 e1, const int p) {
        float er[8];
        er[0]=e0.x; er[1]=e0.y; er[2]=e0.z; er[3]=e0.w;
        er[4]=e1.x; er[5]=e1.y; er[6]=e1.z; er[7]=e1.w;
        float acc[HH];
#pragma unroll
        for (int h = 0; h < HH; ++h) {
            float s = er[0] * ev[h][0];
#pragma unroll
            for (int u = 1; u < 8; ++u) s = fmaf(er[u], ev[h][u], s);
            acc[h] = s;
        }
        // fold 16 lanes -> lane dc holds head dc>>1 (dc even writes)
        float t4[4];
#pragma unroll
        for (int j = 0; j < 4; ++j) {
            const float keep = hi8 ? acc[j + 4] : acc[j];
            const float send = hi8 ? acc[j]     : acc[j + 4];
            t4[j] = keep + __shfl_xor(send, 8);
        }
        float t2[2];
#pragma unroll
        for (int j = 0; j < 2; ++j) {
            const float keep = hi4 ? t4[j + 2] : t4[j];
            const float send = hi4 ? t4[j]     : t4[j + 2];
            t2[j] = keep + __shfl_xor(send, 4);
        }
        float w;
        {
            const float keep = hi2 ? t2[1] : t2[0];
            const float send = hi2 ? t2[0] : t2[1];
            w = keep + __shfl_xor(send, 2);
        }
        w += __shfl_xor(w, 1);
        if ((dc & 1) == 0) comp[dc >> 1][wave * 128 + p * 4 + sub] = w;
    };

#define LDE(B0, B1, p) { const float* _p = epl + (size_t)(p) * 512; \
                         B0 = *(const float4*)_p; B1 = *(const float4*)(_p + 4); }

    float4 A0, A1, B0, B1, C0, C1;
    LDE(A0, A1, 0); LDE(B0, B1, 1);
    for (int p = 0; p < 30; p += 3) {          // 2-ahead, static names
        LDE(C0, C1, p + 2); do_pass(A0, A1, p);
        LDE(A0, A1, p + 3); do_pass(B0, B1, p + 1);
        LDE(B0, B1, p + 4); do_pass(C0, C1, p + 2);
    }
    do_pass(A0, A1, 30); do_pass(B0, B1, 31);
#undef LDE
    __syncthreads();

    // ---- softmax + PV: wave handles heads 2w, 2w+1 ----
#pragma unroll
    for (int hh = 0; hh < 2; ++hh) {
        const int h = wave * 2 + hh;
        const float* qk   = QKT + ((size_t)bn * HH + h) * NN;       // coalesced
        const float* vrow = Vt + ((size_t)b * DD + h * KK) * NN;    // + v*NN + m

        float s[8];
#pragma unroll
        for (int i = 0; i < 8; ++i)
            s[i] = comp[h][lane + i * 64] + qk[lane + i * 64];

        float mx = s[0];
#pragma unroll
        for (int i = 1; i < 8; ++i) mx = fmaxf(mx, s[i]);
#pragma unroll
        for (int mask = 1; mask <= 32; mask <<= 1)
            mx = fmaxf(mx, __shfl_xor(mx, mask));

        float pr[8], psum = 0.f;
#pragma unroll
        for (int i = 0; i < 8; ++i) { pr[i] = __expf(s[i] - mx); psum += pr[i]; }

        float av[KK];
#pragma unroll
        for (int v = 0; v < KK; ++v) av[v] = 0.f;
#pragma unroll
        for (int v = 0; v < KK; ++v) {
            const float* vp = vrow + (size_t)v * NN + lane;
#pragma unroll
            for (int i = 0; i < 8; ++i)
                av[v] = fmaf(pr[i], vp[i * 64], av[v]);   // coalesced dwords
        }
#pragma unroll
        for (int mask = 1; mask <= 32; mask <<= 1)
            psum += __shfl_xor(psum, mask);

        // av[16] fold over 64 lanes: lane (lane&3)==0 owns v = lane>>2
        const bool s5 = (lane & 32) != 0;
        float a8[8];
#pragma unroll
        for (int j = 0; j < 8; ++j) {
            const float keep = s5 ? av[j + 8] : av[j];
            const float send = s5 ? av[j]     : av[j + 8];
            a8[j] = keep + __shfl_xor(send, 32);
        }
        const bool s4 = (lane & 16) != 0;
        float a4[4];
#pragma unroll
        for (int j = 0; j < 4; ++j) {
            const float keep = s4 ? a8[j + 4] : a8[j];
            const float send = s4 ? a8[j]     : a8[j + 4];
            a4[j] = keep + __shfl_xor(send, 16);
        }
        const bool s3 = (lane & 8) != 0;
        float a2[2];
#pragma unroll
        for (int j = 0; j < 2; ++j) {
            const float keep = s3 ? a4[j + 2] : a4[j];
            const float send = s3 ? a4[j]     : a4[j + 2];
            a2[j] = keep + __shfl_xor(send, 8);
        }
        const bool s2 = (lane & 4) != 0;
        float a1;
        {
            const float keep = s2 ? a2[1] : a2[0];
            const float send = s2 ? a2[0] : a2[1];
            a1 = keep + __shfl_xor(send, 4);
        }
        a1 += __shfl_xor(a1, 2);
        a1 += __shfl_xor(a1, 1);
        if ((lane & 3) == 0)
            headsv[h * KK + (lane >> 2)] = a1 / psum;
    }
    __syncthreads();

    // ---- out projection ----
    if (tid < DD) {
        float o = 0.f;
#pragma unroll 8
        for (int p = 0; p < HH * KK; ++p)
            o = fmaf(headsv[p], Wout[(size_t)p * DD + tid], o);
        out[(size_t)bn * DD + tid] = o;
    }
}

extern "C" void kernel_launch(void* const* d_in, const int* in_sizes, int n_in,
                              void* d_out, int out_size, void* d_ws, size_t ws_size,
                              hipStream_t stream) {
    const float* q    = (const float*)d_in[0];
    const float* e    = (const float*)d_in[1];
    const float* Wq   = (const float*)d_in[2];
    const float* Wk   = (const float*)d_in[3];
    const float* Wv   = (const float*)d_in[4];
    const float* Ev   = (const float*)d_in[5];
    const float* Wout = (const float*)d_in[6];
    float* out = (float*)d_out;

    float* Qs  = (float*)d_ws;                    // [B][N][128]   1 MB
    float* Kp  = Qs  + (size_t)BB * NN * DD;      // [B][N][128]   1 MB
    float* Vp  = Kp  + (size_t)BB * NN * DD;      // [B][N][128]   1 MB
    float* Vt  = Vp  + (size_t)BB * NN * DD;      // [B][128][N]   1 MB
    float* QKT = Vt  + (size_t)BB * DD * NN;      // [B][N][H][N]  33.5 MB

    proj_kernel<<<BB * NN, 128, 0, stream>>>(q, Wq, Wk, Wv, Qs, Kp, Vp);
    vt_kernel<<<BB * 8, 256, 0, stream>>>(Vp, Vt);
    qkt_kernel<<<BB * 128, 256, 0, stream>>>(Qs, Kp, QKT);
    attn_kernel<<<BB * NN, 256, 0, stream>>>(e, Ev, QKT, Vt, Wout, out);
}